// Round 3
// baseline (470.458 us; speedup 1.0000x reference)
//
#include <hip/hip_runtime.h>
#include <hip/hip_fp16.h>

// RelativeMultiHeadAttention on MI355X (gfx950), fp16 MFMA pipeline. Round 3.
//
// R3 changes (flash DS-pipe bound: ~900 DS cyc/wave/tile):
//  - swapped score MFMAs (S^T = K Q^T, Qr^T = band Q^T): lane owns a full score
//    row -> softmax cross-lane 32 swizzles -> 4; skew/P writes b64-packed
//  - T14 async staging in flash: preload K/V/Rb->regs during prev tile compute
//  - qkv/out_proj: register prefetch double-buffer (hide HBM latency)
//  - out_proj converts wo fp32->f16 during staging (one less cvt kernel)
//
// MFMA 16x16x32_f16 fragment convention (m97-verified):
//   A/B operand: row/col = lane&15, k = 8*(lane>>4)+j (8 contiguous halves)
//   C/D:         col = lane&15 (B idx), row = 4*(lane>>4)+reg (A idx)

typedef _Float16 f16;
typedef _Float16 f16x4 __attribute__((ext_vector_type(4)));
typedef _Float16 f16x8 __attribute__((ext_vector_type(8)));
typedef float    f32x4 __attribute__((ext_vector_type(4)));

#define NBATCH 2
#define NHEADS 16
#define DKDIM  64
#define SEQL   2048
#define DMODEL 1024
#define NTOK   4096
#define MAXLEN 2048

// ---------------------------------------------------------------- K0: convert
__global__ void cvt_f32_f16(const float* __restrict__ src, f16* __restrict__ dst, int n4) {
    int i = blockIdx.x * blockDim.x + threadIdx.x;
    if (i < n4) {
        float4 v = ((const float4*)src)[i];
        f16x4 h = { (f16)v.x, (f16)v.y, (f16)v.z, (f16)v.w };
        ((f16x4*)dst)[i] = h;
    }
}

// ------------------------------------------------------------ K1: QKV project
// C[n,o] = sum_i X[n,i]*W[o,i] + b[o]; 128x128 tile, 4 waves (2x2), BK=64,
// register-prefetch double buffer.
__global__ __launch_bounds__(256, 2) void qkv_proj(
    const float* __restrict__ qg, const float* __restrict__ kg, const float* __restrict__ vg,
    const float* __restrict__ wq, const float* __restrict__ wk, const float* __restrict__ wv,
    const float* __restrict__ bq, const float* __restrict__ bk, const float* __restrict__ bv,
    f16* __restrict__ qh, f16* __restrict__ kh, f16* __restrict__ vt)
{
    const int which = blockIdx.z;
    const float* X    = which == 0 ? qg : (which == 1 ? kg : vg);
    const float* W    = which == 0 ? wq : (which == 1 ? wk : wv);
    const float* bias = which == 0 ? bq : (which == 1 ? bk : bv);

    __shared__ f16 As[128][72];
    __shared__ f16 Bs[128][72];

    const int tid = threadIdx.x;
    const int lane = tid & 63;
    const int w = tid >> 6;
    const int wr = w >> 1, wc = w & 1;
    const int row0 = blockIdx.y * 128;
    const int col0 = blockIdx.x * 128;

    f32x4 acc[4][4] = {};
    float4 ra[8], rw[8];

    // prefetch k-chunk 0
    #pragma unroll
    for (int rep = 0; rep < 8; ++rep) {
        int idx = rep * 256 + tid;
        int r = idx >> 4, seg = idx & 15;
        ra[rep] = *(const float4*)&X[(size_t)(row0 + r) * DMODEL + seg * 4];
        rw[rep] = *(const float4*)&W[(size_t)(col0 + r) * DMODEL + seg * 4];
    }

    for (int kk = 0; kk < DMODEL; kk += 64) {
        #pragma unroll
        for (int rep = 0; rep < 8; ++rep) {
            int idx = rep * 256 + tid;
            int r = idx >> 4, seg = idx & 15;
            f16x4 ha = { (f16)ra[rep].x, (f16)ra[rep].y, (f16)ra[rep].z, (f16)ra[rep].w };
            *(f16x4*)&As[r][seg * 4] = ha;
            f16x4 hb = { (f16)rw[rep].x, (f16)rw[rep].y, (f16)rw[rep].z, (f16)rw[rep].w };
            *(f16x4*)&Bs[r][seg * 4] = hb;
        }
        __syncthreads();
        if (kk + 64 < DMODEL) {
            #pragma unroll
            for (int rep = 0; rep < 8; ++rep) {
                int idx = rep * 256 + tid;
                int r = idx >> 4, seg = idx & 15;
                ra[rep] = *(const float4*)&X[(size_t)(row0 + r) * DMODEL + kk + 64 + seg * 4];
                rw[rep] = *(const float4*)&W[(size_t)(col0 + r) * DMODEL + kk + 64 + seg * 4];
            }
        }
        f16x8 a[4][2], b[4][2];
        #pragma unroll
        for (int mi = 0; mi < 4; ++mi)
            #pragma unroll
            for (int ks = 0; ks < 2; ++ks)
                a[mi][ks] = *(const f16x8*)&As[wr * 64 + mi * 16 + (lane & 15)][ks * 32 + (lane >> 4) * 8];
        #pragma unroll
        for (int ni = 0; ni < 4; ++ni)
            #pragma unroll
            for (int ks = 0; ks < 2; ++ks)
                b[ni][ks] = *(const f16x8*)&Bs[wc * 64 + ni * 16 + (lane & 15)][ks * 32 + (lane >> 4) * 8];
        __builtin_amdgcn_s_setprio(1);
        #pragma unroll
        for (int mi = 0; mi < 4; ++mi)
            #pragma unroll
            for (int ni = 0; ni < 4; ++ni)
                #pragma unroll
                for (int ks = 0; ks < 2; ++ks)
                    acc[mi][ni] = __builtin_amdgcn_mfma_f32_16x16x32_f16(a[mi][ks], b[ni][ks], acc[mi][ni], 0, 0, 0);
        __builtin_amdgcn_s_setprio(0);
        __syncthreads();
    }

    // epilogue: +bias, scatter into head layouts
    #pragma unroll
    for (int mi = 0; mi < 4; ++mi) {
        #pragma unroll
        for (int ni = 0; ni < 4; ++ni) {
            int col = col0 + wc * 64 + ni * 16 + (lane & 15);
            int h = col >> 6, d = col & 63;
            float bc = bias[col];
            int rowb = row0 + wr * 64 + mi * 16 + (lane >> 4) * 4;
            int b_ = rowb >> 11, l0 = rowb & 2047;
            if (which == 2) {
                f16x4 pk = { (f16)(acc[mi][ni][0] + bc), (f16)(acc[mi][ni][1] + bc),
                             (f16)(acc[mi][ni][2] + bc), (f16)(acc[mi][ni][3] + bc) };
                *(f16x4*)&vt[((size_t)((b_ * 16 + h) * 64 + d)) * 2048 + l0] = pk;
            } else {
                f16* dst = (which == 0) ? qh : kh;
                #pragma unroll
                for (int r = 0; r < 4; ++r)
                    dst[((size_t)((b_ * 16 + h) * 2048 + l0 + r)) * 64 + d] = (f16)(acc[mi][ni][r] + bc);
            }
        }
    }
}

// --------------------------------------------------------- K2: flash attention
// 4 waves; wave w owns Q rows [i0+16w, i0+16w+16). K/V tiles = 64. Swapped-score
// layout: lane holds full score row i = lane&15. Async reg-staged K/V/Rb.
__global__ __launch_bounds__(256, 3) void flash_attn(
    const f16* __restrict__ qh, const f16* __restrict__ kh, const f16* __restrict__ vt,
    const f16* __restrict__ rel, f16* __restrict__ att)
{
    const int tid = threadIdx.x, lane = tid & 63, w = tid >> 6;
    const int i_l = lane & 15, hi = lane >> 4;
    const int bh = blockIdx.y;
    const int b = bh >> 4, h = bh & 15;
    const int i0 = blockIdx.x * 64;

    __shared__ f16 Ks[64][72];          // K tile (prologue: Q stage)
    __shared__ f16 Vs[64][72];          // Vs[d][j]
    __shared__ f16 Rb[128][72];         // rolling rel band, slot = p & 127
    __shared__ f16 Qb[4][16][88];       // per-wave: band cols 0..78 / P cols 0..63

    const size_t base_kq = (size_t)bh * SEQL * DKDIM;
    const int pb0 = MAXLEN - i0 - 63;   // abs rel row of window start at j0=0 (>=1)

    // ---- prologue: stage Q into Ks; stage Rb rows [pb0, pb0+64)
    #pragma unroll
    for (int rep = 0; rep < 2; ++rep) {
        int idx = rep * 256 + tid;
        int r = idx >> 3, seg = idx & 7;
        *(int4*)&Ks[r][seg * 8] = *(const int4*)&qh[base_kq + (size_t)(i0 + r) * 64 + seg * 8];
        int p = pb0 + r;
        *(int4*)&Rb[p & 127][seg * 8] = *(const int4*)&rel[(size_t)p * 64 + seg * 8];
    }
    __syncthreads();
    f16x8 aq[2];                        // Q fragment (B-operand now), per-wave rows
    aq[0] = *(const f16x8*)&Ks[w * 16 + i_l][hi * 8];
    aq[1] = *(const f16x8*)&Ks[w * 16 + i_l][32 + hi * 8];

    // preload tile 0 (K/V) + Rb rows [pb0+64, pb0+128)
    int4 rk[2], rv[2], rr[2];
    #pragma unroll
    for (int rep = 0; rep < 2; ++rep) {
        int idx = rep * 256 + tid;
        int r = idx >> 3, seg = idx & 7;
        rk[rep] = *(const int4*)&kh[base_kq + (size_t)r * 64 + seg * 8];
        rv[rep] = *(const int4*)&vt[base_kq + (size_t)r * 2048 + seg * 8];
        int p = pb0 + 64 + r; if (p > 4095) p = 4095;
        rr[rep] = *(const int4*)&rel[(size_t)p * 64 + seg * 8];
    }
    __syncthreads();                    // aq read before Ks overwritten

    float mrun = -1e30f, lrun = 0.f;    // per-lane = per score row i
    f32x4 oacc[4] = {};
    const int p0w_off = 48 - w * 16;

    for (int j0 = 0; j0 < SEQL; j0 += 64) {
        // ---- write staged regs -> LDS
        #pragma unroll
        for (int rep = 0; rep < 2; ++rep) {
            int idx = rep * 256 + tid;
            int r = idx >> 3, seg = idx & 7;
            *(int4*)&Ks[r][seg * 8] = rk[rep];
            *(int4*)&Vs[r][seg * 8] = rv[rep];
            *(int4*)&Rb[(pb0 + j0 + 64 + r) & 127][seg * 8] = rr[rep];
        }
        __syncthreads();

        // ---- preload next tile (overlaps compute)
        if (j0 + 64 < SEQL) {
            #pragma unroll
            for (int rep = 0; rep < 2; ++rep) {
                int idx = rep * 256 + tid;
                int r = idx >> 3, seg = idx & 7;
                rk[rep] = *(const int4*)&kh[base_kq + (size_t)(j0 + 64 + r) * 64 + seg * 8];
                rv[rep] = *(const int4*)&vt[base_kq + (size_t)r * 2048 + j0 + 64 + seg * 8];
                int p = pb0 + j0 + 128 + r;
                int slot_p = p; if (slot_p > 4095) slot_p = 4095;
                rr[rep] = *(const int4*)&rel[(size_t)slot_p * 64 + seg * 8];
            }
        }

        // ---- S^T = K Q^T (A = K rows, B = Q); Qr^T = band Q^T
        const int p0w = pb0 + j0 + p0w_off;
        f32x4 sacc[4] = {};
        f32x4 qracc[5] = {};
        __builtin_amdgcn_s_setprio(1);
        #pragma unroll
        for (int jf = 0; jf < 4; ++jf)
            #pragma unroll
            for (int ks = 0; ks < 2; ++ks) {
                f16x8 ak = *(const f16x8*)&Ks[jf * 16 + i_l][ks * 32 + hi * 8];
                sacc[jf] = __builtin_amdgcn_mfma_f32_16x16x32_f16(ak, aq[ks], sacc[jf], 0, 0, 0);
            }
        #pragma unroll
        for (int pf = 0; pf < 5; ++pf)
            #pragma unroll
            for (int ks = 0; ks < 2; ++ks) {
                f16x8 ar = *(const f16x8*)&Rb[(p0w + pf * 16 + i_l) & 127][ks * 32 + hi * 8];
                qracc[pf] = __builtin_amdgcn_mfma_f32_16x16x32_f16(ar, aq[ks], qracc[pf], 0, 0, 0);
            }
        __builtin_amdgcn_s_setprio(0);

        // ---- band -> per-wave LDS, b64-packed: row i_l, 4 consecutive t per reg-quad
        #pragma unroll
        for (int pf = 0; pf < 5; ++pf) {
            f16x4 pk = { (f16)qracc[pf][0], (f16)qracc[pf][1], (f16)qracc[pf][2], (f16)qracc[pf][3] };
            *(f16x4*)&Qb[w][i_l][pf * 16 + 4 * hi] = pk;
        }

        // ---- skew read + scale: p_[nf][r] for (i = i_l, j = nf*16 + 4*hi + r)
        float p_[4][4];
        #pragma unroll
        for (int nf = 0; nf < 4; ++nf)
            #pragma unroll
            for (int r = 0; r < 4; ++r) {
                int t = nf * 16 + 4 * hi + r - i_l + 15;   // 0..78
                p_[nf][r] = (sacc[nf][r] + (float)Qb[w][i_l][t]) * 0.125f;
            }

        // ---- per-row online softmax (row = lane, only xor16/xor32 cross ops)
        float mx = fmaxf(fmaxf(fmaxf(p_[0][0], p_[0][1]), fmaxf(p_[0][2], p_[0][3])),
                         fmaxf(fmaxf(p_[1][0], p_[1][1]), fmaxf(p_[1][2], p_[1][3])));
        mx = fmaxf(mx, fmaxf(fmaxf(fmaxf(p_[2][0], p_[2][1]), fmaxf(p_[2][2], p_[2][3])),
                             fmaxf(fmaxf(p_[3][0], p_[3][1]), fmaxf(p_[3][2], p_[3][3]))));
        mx = fmaxf(mx, __shfl_xor(mx, 16, 64));
        mx = fmaxf(mx, __shfl_xor(mx, 32, 64));
        float mnew = fmaxf(mrun, mx);
        float sc = __expf(mrun - mnew);
        float sm = 0.f;
        #pragma unroll
        for (int nf = 0; nf < 4; ++nf) {
            #pragma unroll
            for (int r = 0; r < 4; ++r) { p_[nf][r] = __expf(p_[nf][r] - mnew); }
            sm += (p_[nf][0] + p_[nf][1]) + (p_[nf][2] + p_[nf][3]);
        }
        sm += __shfl_xor(sm, 16, 64);
        sm += __shfl_xor(sm, 32, 64);
        lrun = lrun * sc + sm;
        mrun = mnew;

        // ---- broadcast scale to D-layout rows (row of oacc = 4*hi + r)
        float scb[4];
        #pragma unroll
        for (int r = 0; r < 4; ++r)
            scb[r] = __shfl(sc, (lane & 48) | (4 * hi + r), 64);
        #pragma unroll
        for (int df = 0; df < 4; ++df)
            #pragma unroll
            for (int r = 0; r < 4; ++r) oacc[df][r] *= scb[r];

        // ---- P -> per-wave LDS (b64-packed), then PV
        #pragma unroll
        for (int nf = 0; nf < 4; ++nf) {
            f16x4 pk = { (f16)p_[nf][0], (f16)p_[nf][1], (f16)p_[nf][2], (f16)p_[nf][3] };
            *(f16x4*)&Qb[w][i_l][nf * 16 + 4 * hi] = pk;
        }
        f16x8 pa[2];
        pa[0] = *(const f16x8*)&Qb[w][i_l][hi * 8];
        pa[1] = *(const f16x8*)&Qb[w][i_l][32 + hi * 8];
        __builtin_amdgcn_s_setprio(1);
        #pragma unroll
        for (int df = 0; df < 4; ++df)
            #pragma unroll
            for (int ks = 0; ks < 2; ++ks) {
                f16x8 bv = *(const f16x8*)&Vs[df * 16 + i_l][ks * 32 + hi * 8];
                oacc[df] = __builtin_amdgcn_mfma_f32_16x16x32_f16(pa[ks], bv, oacc[df], 0, 0, 0);
            }
        __builtin_amdgcn_s_setprio(0);
        __syncthreads();   // WAR: next iteration overwrites Ks/Vs/Rb
    }

    // ---- epilogue: broadcast lrun to D-layout rows, normalize, write att
    float lb[4];
    #pragma unroll
    for (int r = 0; r < 4; ++r)
        lb[r] = __shfl(lrun, (lane & 48) | (4 * hi + r), 64);
    #pragma unroll
    for (int df = 0; df < 4; ++df) {
        int d = df * 16 + i_l;
        #pragma unroll
        for (int r = 0; r < 4; ++r) {
            int i = i0 + w * 16 + 4 * hi + r;
            float val = oacc[df][r] / lb[r];
            att[((size_t)(b * 2048 + i)) * DMODEL + h * 64 + d] = (f16)val;
        }
    }
}

// ------------------------------------------------------------- K3: out project
__global__ __launch_bounds__(256, 2) void out_proj(
    const f16* __restrict__ att, const float* __restrict__ wo, const float* __restrict__ bo,
    float* __restrict__ out)
{
    __shared__ f16 As[128][72];
    __shared__ f16 Bs[128][72];
    const int tid = threadIdx.x, lane = tid & 63, w = tid >> 6;
    const int wr = w >> 1, wc = w & 1;
    const int row0 = blockIdx.y * 128, col0 = blockIdx.x * 128;

    f32x4 acc[4][4] = {};
    int4 pa_[4];
    float4 pw[8];

    #pragma unroll
    for (int rep = 0; rep < 4; ++rep) {
        int idx = rep * 256 + tid;
        int r = idx >> 3, seg = idx & 7;
        pa_[rep] = *(const int4*)&att[(size_t)(row0 + r) * DMODEL + seg * 8];
    }
    #pragma unroll
    for (int rep = 0; rep < 8; ++rep) {
        int idx = rep * 256 + tid;
        int r = idx >> 4, seg = idx & 15;
        pw[rep] = *(const float4*)&wo[(size_t)(col0 + r) * DMODEL + seg * 4];
    }

    for (int kk = 0; kk < DMODEL; kk += 64) {
        #pragma unroll
        for (int rep = 0; rep < 4; ++rep) {
            int idx = rep * 256 + tid;
            int r = idx >> 3, seg = idx & 7;
            *(int4*)&As[r][seg * 8] = pa_[rep];
        }
        #pragma unroll
        for (int rep = 0; rep < 8; ++rep) {
            int idx = rep * 256 + tid;
            int r = idx >> 4, seg = idx & 15;
            f16x4 hb = { (f16)pw[rep].x, (f16)pw[rep].y, (f16)pw[rep].z, (f16)pw[rep].w };
            *(f16x4*)&Bs[r][seg * 4] = hb;
        }
        __syncthreads();
        if (kk + 64 < DMODEL) {
            #pragma unroll
            for (int rep = 0; rep < 4; ++rep) {
                int idx = rep * 256 + tid;
                int r = idx >> 3, seg = idx & 7;
                pa_[rep] = *(const int4*)&att[(size_t)(row0 + r) * DMODEL + kk + 64 + seg * 8];
            }
            #pragma unroll
            for (int rep = 0; rep < 8; ++rep) {
                int idx = rep * 256 + tid;
                int r = idx >> 4, seg = idx & 15;
                pw[rep] = *(const float4*)&wo[(size_t)(col0 + r) * DMODEL + kk + 64 + seg * 4];
            }
        }
        f16x8 a[4][2], b[4][2];
        #pragma unroll
        for (int mi = 0; mi < 4; ++mi)
            #pragma unroll
            for (int ks = 0; ks < 2; ++ks)
                a[mi][ks] = *(const f16x8*)&As[wr * 64 + mi * 16 + (lane & 15)][ks * 32 + (lane >> 4) * 8];
        #pragma unroll
        for (int ni = 0; ni < 4; ++ni)
            #pragma unroll
            for (int ks = 0; ks < 2; ++ks)
                b[ni][ks] = *(const f16x8*)&Bs[wc * 64 + ni * 16 + (lane & 15)][ks * 32 + (lane >> 4) * 8];
        __builtin_amdgcn_s_setprio(1);
        #pragma unroll
        for (int mi = 0; mi < 4; ++mi)
            #pragma unroll
            for (int ni = 0; ni < 4; ++ni)
                #pragma unroll
                for (int ks = 0; ks < 2; ++ks)
                    acc[mi][ni] = __builtin_amdgcn_mfma_f32_16x16x32_f16(a[mi][ks], b[ni][ks], acc[mi][ni], 0, 0, 0);
        __builtin_amdgcn_s_setprio(0);
        __syncthreads();
    }

    #pragma unroll
    for (int mi = 0; mi < 4; ++mi)
        #pragma unroll
        for (int ni = 0; ni < 4; ++ni) {
            int col = col0 + wc * 64 + ni * 16 + (lane & 15);
            float bc = bo[col];
            #pragma unroll
            for (int r = 0; r < 4; ++r) {
                int row = row0 + wr * 64 + mi * 16 + (lane >> 4) * 4 + r;
                out[(size_t)row * DMODEL + col] = acc[mi][ni][r] + bc;
            }
        }
}

// ----------------------------------------------------------------- launch
extern "C" void kernel_launch(void* const* d_in, const int* in_sizes, int n_in,
                              void* d_out, int out_size, void* d_ws, size_t ws_size,
                              hipStream_t stream) {
    const float* q   = (const float*)d_in[0];
    const float* k   = (const float*)d_in[1];
    const float* v   = (const float*)d_in[2];
    const float* rel = (const float*)d_in[3];
    const float* wq  = (const float*)d_in[4];
    const float* bq  = (const float*)d_in[5];
    const float* wk  = (const float*)d_in[6];
    const float* bk  = (const float*)d_in[7];
    const float* wv  = (const float*)d_in[8];
    const float* bv  = (const float*)d_in[9];
    const float* wo  = (const float*)d_in[10];
    const float* bo  = (const float*)d_in[11];
    float* out = (float*)d_out;

    // workspace layout (halves): rel16 | qh | kh | vt | att
    f16* ws    = (f16*)d_ws;
    f16* rel16 = ws;
    f16* qh16  = rel16 + (size_t)2 * MAXLEN * DKDIM;
    f16* kh16  = qh16 + (size_t)NTOK * DMODEL;
    f16* vt16  = kh16 + (size_t)NTOK * DMODEL;
    f16* att16 = vt16 + (size_t)NTOK * DMODEL;

    cvt_f32_f16<<<dim3(256), 256, 0, stream>>>(rel, rel16, 2 * MAXLEN * DKDIM / 4);
    qkv_proj<<<dim3(8, 32, 3), 256, 0, stream>>>(q, k, v, wq, wk, wv, bq, bk, bv,
                                                 qh16, kh16, vt16);
    flash_attn<<<dim3(32, 32), 256, 0, stream>>>(qh16, kh16, vt16, rel16, att16);
    out_proj<<<dim3(8, 32), 256, 0, stream>>>(att16, wo, bo, out);
}